// Round 1
// baseline (515.083 us; speedup 1.0000x reference)
//
#include <hip/hip_runtime.h>

namespace {

constexpr int T = 1024;
constexpr int B = 1024;
constexpr int L = 10;
constexpr int H = 10;
constexpr int NTHREADS = 128;       // 2 waves: wave0 = layers 0-5, wave1 = layers 6-9
constexpr int U = 4;                // timesteps per interval
constexpr int NWIN = T / U;         // 256 windows
constexpr int NINT = NWIN + L - 1;  // 265 intervals
constexpr int BH = B * H;
constexpr int WSLOT = 84;           // 80 weights + 4 fused biases per (l,j)

using v2f = __attribute__((ext_vector_type(2))) float;

__device__ __forceinline__ v2f v2fma(v2f a, v2f b, v2f c) {
    return __builtin_elementwise_fma(a, b, c);   // v_pk_fma_f32
}
__device__ __forceinline__ void pin2(v2f& v) { asm volatile("" : "+v"(v)); }

__device__ __forceinline__ float sigmoid_f(float x) {
    return __builtin_amdgcn_rcpf(1.0f + __expf(-x));
}
__device__ __forceinline__ float tanh_f(float x) {
    return 1.0f - 2.0f * __builtin_amdgcn_rcpf(1.0f + __expf(2.0f * x));
}

__global__
__attribute__((amdgpu_flat_work_group_size(NTHREADS, NTHREADS)))
__attribute__((amdgpu_waves_per_eu(2)))   // cap VGPR at 256: protect 2-wave/SIMD residency
void lstm_pipeline(const float* __restrict__ x,    // [T,B,H]
                   const float* __restrict__ hp,   // [L,B,H]
                   const float* __restrict__ cp,   // [L,B,H]
                   const float* __restrict__ Wih,  // [L,4H,H]
                   const float* __restrict__ Whh,  // [L,4H,H]
                   const float* __restrict__ bih,  // [L,4H]
                   const float* __restrict__ bhh,  // [L,4H]
                   float* __restrict__ out,        // [T,B,H]
                   float* __restrict__ hn,         // [L,B,H]
                   float* __restrict__ cn)         // [L,B,H]
{
    __shared__ __align__(16) float wlds[L * H * WSLOT];   // 33.6 KB staging
    // Layer stride = 12 floats (not 96): 6 distinct l per wave -> disjoint banks.
    __shared__ __align__(16) float buf[2][U][L + 1][12];
    __shared__ __align__(16) float hbuf[L][12];           // wave-local h rows

    const int tid = threadIdx.x;
    const int wv = tid >> 6, ln = tid & 63;
    // Every lane gets a valid (l,j); lanes beyond the 100 primaries duplicate
    // existing work (same inputs -> same values -> same addresses; benign).
    int lidx;
    if (wv == 0) lidx = (ln < 60) ? ln : (ln - 10);            // dup l=5,j=0..3
    else         lidx = (ln < 40) ? (60 + ln) : (90 + (ln - 40) % 10);  // dup l=9
    const int l = lidx / 10;
    const int j = lidx % 10;
    const int b = blockIdx.x;
    const int boff = b * H + j;

    // ---- one-time: stage this thread's weights to LDS (unconditional) ----
    {
        float* slot = &wlds[lidx * WSLOT];
        #pragma unroll
        for (int g = 0; g < 4; ++g) {
            const int row = l * 4 * H + g * H + j;
            const float* wr = Wih + (size_t)row * H;
            const float* hr = Whh + (size_t)row * H;
            #pragma unroll
            for (int i = 0; i < H; ++i) slot[g * H + i] = wr[i];
            #pragma unroll
            for (int i = 0; i < H; ++i) slot[40 + g * H + i] = hr[i];
            slot[80 + g] = bih[row] + bhh[row];
        }
    }
    __syncthreads();

    // ---- read back into pinned registers ----
    v2f wi2[4][5], wh2[4][5], biasv[4];
    {
        const float* slot = &wlds[lidx * WSLOT];
        #pragma unroll
        for (int g = 0; g < 4; ++g) {
            #pragma unroll
            for (int p = 0; p < 5; ++p) {
                wi2[g][p] = *(const v2f*)&slot[g * H + 2 * p];
                wh2[g][p] = *(const v2f*)&slot[40 + g * H + 2 * p];
            }
            biasv[g][0] = slot[80 + g];   // bias folded into first FMA addend
            biasv[g][1] = 0.0f;
        }
    }
    #pragma unroll
    for (int g = 0; g < 4; ++g) {
        #pragma unroll
        for (int p = 0; p < 5; ++p) { pin2(wi2[g][p]); pin2(wh2[g][p]); }
        pin2(biasv[g]);
    }

    float h = hp[(l * B + b) * H + j];
    float c = cp[(l * B + b) * H + j];
    hbuf[l][j] = h;                           // h(-1)

    float xcur[U], xnext[U];
    if (lidx < 10) {                          // layer-0 primaries stage x
        #pragma unroll
        for (int u = 0; u < U; ++u) buf[1][u][0][j] = x[(size_t)u * BH + boff];
        #pragma unroll
        for (int u = 0; u < U; ++u) xcur[u] = x[(size_t)(U + u) * BH + boff];
    }
    __syncthreads();

    auto interval = [&](int k, int wp, int rp) {
        // Prefetch x window k+2 (drain amortized to once per interval).
        if (lidx < 10 && (k + 2) < NWIN) {
            #pragma unroll
            for (int u = 0; u < U; ++u)
                xnext[u] = x[(size_t)((k + 2) * U + u) * BH + boff];
        }
        const unsigned w = (unsigned)(k - l);
        if (w < (unsigned)NWIN) {
            // u=0 hin row is barrier-stable: preload it before phase 1 so the
            // first recurrence step starts with zero LDS wait.
            float hin0[10];
            {
                const float* hr = &hbuf[l][0];
                *(float4*)&hin0[0] = *(const float4*)(hr);
                *(float4*)&hin0[4] = *(const float4*)(hr + 4);
                *(float2*)&hin0[8] = *(const float2*)(hr + 8);
            }
            // ---- phase 1: all 4 timesteps' x-projections (h-independent) ----
            float xin[U][10];
            #pragma unroll
            for (int u = 0; u < U; ++u) {
                const float* xr = &buf[rp][u][l][0];
                *(float4*)&xin[u][0] = *(const float4*)(xr);
                *(float4*)&xin[u][4] = *(const float4*)(xr + 4);
                *(float2*)&xin[u][8] = *(const float2*)(xr + 8);
            }
            v2f acc[U][4];
            #pragma unroll
            for (int u = 0; u < U; ++u) {
                #pragma unroll
                for (int p = 0; p < 5; ++p) {
                    v2f xp; xp[0] = xin[u][2 * p]; xp[1] = xin[u][2 * p + 1];
                    if (p == 0) {
                        acc[u][0] = v2fma(wi2[0][0], xp, biasv[0]);
                        acc[u][1] = v2fma(wi2[1][0], xp, biasv[1]);
                        acc[u][2] = v2fma(wi2[2][0], xp, biasv[2]);
                        acc[u][3] = v2fma(wi2[3][0], xp, biasv[3]);
                    } else {
                        acc[u][0] = v2fma(wi2[0][p], xp, acc[u][0]);
                        acc[u][1] = v2fma(wi2[1][p], xp, acc[u][1]);
                        acc[u][2] = v2fma(wi2[2][p], xp, acc[u][2]);
                        acc[u][3] = v2fma(wi2[3][p], xp, acc[u][3]);
                    }
                }
            }
            // ---- phase 2: serial recurrence (h-dot + activations only) ----
            float hv[U];
            #pragma unroll
            for (int u = 0; u < U; ++u) {
                float hin[10];
                if (u == 0) {
                    #pragma unroll
                    for (int i = 0; i < 10; ++i) hin[i] = hin0[i];
                } else {
                    const float* hr = &hbuf[l][0];
                    *(float4*)&hin[0] = *(const float4*)(hr);
                    *(float4*)&hin[4] = *(const float4*)(hr + 4);
                    *(float2*)&hin[8] = *(const float2*)(hr + 8);
                }
                v2f a0 = acc[u][0], a1 = acc[u][1], a2 = acc[u][2], a3 = acc[u][3];
                #pragma unroll
                for (int p = 0; p < 5; ++p) {
                    v2f hh; hh[0] = hin[2 * p]; hh[1] = hin[2 * p + 1];
                    a0 = v2fma(wh2[0][p], hh, a0);
                    a1 = v2fma(wh2[1][p], hh, a1);
                    a2 = v2fma(wh2[2][p], hh, a2);
                    a3 = v2fma(wh2[3][p], hh, a3);
                }
                const float ig = sigmoid_f(a0[0] + a0[1]);
                const float fg = sigmoid_f(a1[0] + a1[1]);
                const float gg = tanh_f(a2[0] + a2[1]);
                const float og = sigmoid_f(a3[0] + a3[1]);
                c = fmaf(fg, c, ig * gg);
                h = og * tanh_f(c);

                hbuf[l][j] = h;               // same-wave readers at u+1
                buf[wp][u][l + 1][j] = h;     // l=9 writes pad row 10 (unused)
                hv[u] = h;
            }
            if (l == L - 1) {                 // batched out-stores (dups benign)
                const int t0 = (int)w * U;
                #pragma unroll
                for (int u = 0; u < U; ++u)
                    out[(size_t)(t0 + u) * BH + boff] = hv[u];
            }
        }
        // Stage x window k+1 for the next interval.
        if (lidx < 10 && (k + 1) < NWIN) {
            #pragma unroll
            for (int u = 0; u < U; ++u) buf[wp][u][0][j] = xcur[u];
            #pragma unroll
            for (int u = 0; u < U; ++u) xcur[u] = xnext[u];
        }
        __syncthreads();
    };

    for (int kk = 0; kk < NINT + 1; kk += 2) {   // literal parities
        interval(kk, 0, 1);
        interval(kk + 1, 1, 0);
    }

    hn[(l * B + b) * H + j] = h;   // duplicates store identical values
    cn[(l * B + b) * H + j] = c;
}

} // namespace

extern "C" void kernel_launch(void* const* d_in, const int* in_sizes, int n_in,
                              void* d_out, int out_size, void* d_ws, size_t ws_size,
                              hipStream_t stream) {
    (void)in_sizes; (void)n_in; (void)d_ws; (void)ws_size; (void)out_size;
    const float* x   = (const float*)d_in[0];
    const float* hp  = (const float*)d_in[1];
    const float* cp  = (const float*)d_in[2];
    const float* Wih = (const float*)d_in[3];
    const float* Whh = (const float*)d_in[4];
    const float* bih = (const float*)d_in[5];
    const float* bhh = (const float*)d_in[6];

    float* out = (float*)d_out;
    float* hn  = out + (size_t)T * B * H;
    float* cn  = hn + (size_t)L * B * H;

    lstm_pipeline<<<dim3(B), dim3(NTHREADS), 0, stream>>>(
        x, hp, cp, Wih, Whh, bih, bhh, out, hn, cn);
}